// Round 9
// baseline (286.335 us; speedup 1.0000x reference)
//
#include <hip/hip_runtime.h>
#include <hip/hip_fp16.h>
#include <math.h>

typedef _Float16 half8 __attribute__((ext_vector_type(8)));
typedef float floatx4 __attribute__((ext_vector_type(4)));

__device__ __forceinline__ float leaky(float v){ return v > 0.f ? v : 0.2f*v; }

__device__ __forceinline__ float wredsum(float v){
  #pragma unroll
  for (int o=32;o>0;o>>=1) v += __shfl_xor(v,o,64);
  return v;
}

// ---------------- graph CSR build (by dst) ----------------
__global__ void k_zero(int* p, int n){
  int i = blockIdx.x*blockDim.x + threadIdx.x;
  if (i < n) p[i] = 0;
}

__global__ void k_hist(const int* __restrict__ dst, int* __restrict__ deg, int E){
  int i = blockIdx.x*blockDim.x + threadIdx.x;
  if (i < E) atomicAdd(&deg[dst[i]], 1);
}

__global__ __launch_bounds__(1024) void k_scan(const int* __restrict__ deg, int* __restrict__ off,
                                               int* __restrict__ cur, int N){
  __shared__ int part[1024];
  int t = threadIdx.x;
  int chunk = (N + 1023) >> 10;
  int c0 = t * chunk;
  int sum = 0;
  for (int i=0;i<chunk;i++){ int idx=c0+i; if (idx < N) sum += deg[idx]; }
  part[t] = sum;
  __syncthreads();
  for (int o=1;o<1024;o<<=1){
    int v = (t >= o) ? part[t-o] : 0;
    __syncthreads();
    part[t] += v;
    __syncthreads();
  }
  int run = part[t] - sum;   // exclusive prefix of this chunk
  for (int i=0;i<chunk;i++){
    int idx = c0+i;
    if (idx < N){ off[idx] = run; cur[idx] = run; run += deg[idx]; }
  }
  if (t == 1023) off[N] = part[1023];
}

__global__ void k_scatter(const int* __restrict__ src, const int* __restrict__ dst,
                          int* __restrict__ cur, int* __restrict__ srcs, int E){
  int i = blockIdx.x*blockDim.x + threadIdx.x;
  if (i < E){ int p = atomicAdd(&cur[dst[i]], 1); srcs[p] = src[i]; }
}

// ---------------- prep: fp16 casts, weight transposes, folded coef vectors ----------------
// xh = fp16(x); w1t[c*64+k]=W1[k*640+c]; w2t[c*64+k]=W2[k*128+c];
// qal1[k*10+h] = sum_c W1[k,h*64+c]*al1[h,c]  (and qar1); qal2[k]=sum_c W2[k,c]*al2[c] (and qar2)
__global__ void k_prep(const float* __restrict__ x, const float* __restrict__ W1,
                       const float* __restrict__ W2,
                       const float* __restrict__ al1, const float* __restrict__ ar1,
                       const float* __restrict__ al2, const float* __restrict__ ar2,
                       __half* __restrict__ xh, __half* __restrict__ w1t, __half* __restrict__ w2t,
                       float* __restrict__ qal1, float* __restrict__ qar1,
                       float* __restrict__ qal2, float* __restrict__ qar2, int nx){
  int i = blockIdx.x*blockDim.x + threadIdx.x;
  if (i < nx){ xh[i] = __float2half(x[i]); return; }
  i -= nx;
  if (i < 640*64){ int c = i >> 6, k = i & 63; w1t[i] = __float2half(W1[k*640 + c]); return; }
  i -= 640*64;
  if (i < 128*64){ int c = i >> 6, k = i & 63; w2t[i] = __float2half(W2[k*128 + c]); return; }
  i -= 128*64;
  if (i < 1280){
    int which = i / 640; int j = i - which*640; int k = j / 10, h = j - k*10;
    const float* av = which ? ar1 : al1;
    float s = 0.f;
    for (int c=0;c<64;c++) s += W1[k*640 + h*64 + c] * av[h*64 + c];
    (which ? qar1 : qal1)[k*10 + h] = s;
    return;
  }
  i -= 1280;
  if (i < 128){
    int which = i >> 6; int k = i & 63;
    const float* av = which ? ar2 : al2;
    float s = 0.f;
    for (int c=0;c<128;c++) s += W2[k*128 + c] * av[c];
    (which ? qar2 : qal2)[k] = s;
    return;
  }
}

// ---------------- attention coefs via folded vectors (fp32 exact-order-free) ----------------
__global__ __launch_bounds__(256) void k_coef1(const float* __restrict__ x,
                                               const float* __restrict__ qal, const float* __restrict__ qar,
                                               float* __restrict__ el, float* __restrict__ er, int N){
  int n = blockIdx.x*4 + (threadIdx.x>>6);
  int lane = threadIdx.x & 63;
  if (n >= N) return;
  float xv = x[(size_t)n*64 + lane];
  #pragma unroll
  for (int h=0; h<10; h++){
    float pl = wredsum(xv * qal[lane*10 + h]);
    float pr = wredsum(xv * qar[lane*10 + h]);
    if (lane == 0){ el[n*10+h] = pl; er[n*10+h] = pr; }
  }
}

__global__ __launch_bounds__(256) void k_coef2(const float* __restrict__ h1f,
                                               const float* __restrict__ qal, const float* __restrict__ qar,
                                               float* __restrict__ el, float* __restrict__ er, int N){
  int n = blockIdx.x*4 + (threadIdx.x>>6);
  int lane = threadIdx.x & 63;
  if (n >= N) return;
  float hv = h1f[(size_t)n*64 + lane];
  float pl = wredsum(hv * qal[lane]);
  float pr = wredsum(hv * qar[lane]);
  if (lane==0){ el[n]=pl; er[n]=pr; }
}

// ---------------- edge-logit pre-gather (CSR order) ----------------
__global__ void k_gel1(const int* __restrict__ srcs, const float* __restrict__ el,
                       float* __restrict__ ge16, int E){
  int t = blockIdx.x*blockDim.x + threadIdx.x;
  if (t >= E*16) return;
  int e = t >> 4, h = t & 15;
  int sv = srcs[e];
  ge16[t] = (h < 10) ? el[sv*10 + h] : -INFINITY;
}

__global__ void k_gel2(const int* __restrict__ srcs, const float* __restrict__ el,
                       float* __restrict__ ge2, int E){
  int e = blockIdx.x*blockDim.x + threadIdx.x;
  if (e < E) ge2[e] = el[srcs[e]];
}

// ---------------- layer1 aggregation: gather 64-dim x rows (L2-resident), 10-head weights ----------------
// agg_h[n,:] = (1/s_h) * sum_e w_{e,h} * x[src_e,:]   -> fp16 [N,10,64]
__global__ __launch_bounds__(64) void k_edge1(const __half* __restrict__ xh,
                                              const float* __restrict__ ge16,
                                              const float* __restrict__ er,
                                              const int* __restrict__ off,
                                              const int* __restrict__ srcs,
                                              __half* __restrict__ aggh, int N){
  const int lane = threadIdx.x;
  const int n = blockIdx.x;
  if (n >= N) return;
  const int beg = off[n], end = off[n+1];
  const int h16 = lane & 15;
  const float erh = (h16 < 10) ? er[n*10 + h16] : 0.f;
  // pass A: streaming max per head
  float mx = -INFINITY;
  for (int i = beg*16 + lane; i < end*16; i += 64) mx = fmaxf(mx, ge16[i]);
  mx = fmaxf(mx, __shfl_xor(mx,16,64));
  mx = fmaxf(mx, __shfl_xor(mx,32,64));
  const float m = (h16 < 10) ? leaky(mx + erh) : 0.f;
  // pass B: weights + x-row gather-accumulate
  float s_acc = 0.f;
  float acc[10] = {0,0,0,0,0,0,0,0,0,0};
  for (int c0 = beg; c0 < end; c0 += 64){
    const int sv = (c0 + lane < end) ? srcs[c0 + lane] : 0;
    const int cn = min(64, end - c0);
    for (int j = 0; j < cn; j += 4){
      const int nv = min(4, cn - j);
      int gi = (c0 + j)*16 + lane;           // 4 edges x 16 head-slots
      float wv = (gi < end*16) ? ge16[gi] : -INFINITY;
      float w = __expf(leaky(wv + erh) - m); // 0 on pad heads/edges
      s_acc += w;
      float xv[4];
      #pragma unroll
      for (int jj=0;jj<4;jj++){
        if (jj < nv){
          int sj = __shfl(sv, j+jj, 64);
          xv[jj] = __half2float(xh[(size_t)sj*64 + lane]);
        }
      }
      #pragma unroll
      for (int jj=0;jj<4;jj++){
        if (jj < nv){
          #pragma unroll
          for (int h=0;h<10;h++)
            acc[h] += __shfl(w, jj*16 + h, 64) * xv[jj];
        }
      }
    }
  }
  float sred = s_acc;
  sred += __shfl_xor(sred,16,64);
  sred += __shfl_xor(sred,32,64);
  const float rs = (h16 < 10 && sred > 0.f) ? 1.f/sred : 0.f;
  #pragma unroll
  for (int h=0;h<10;h++){
    float rh = __shfl(rs, h, 64);
    aggh[(size_t)n*640 + h*64 + lane] = __float2half(acc[h] * rh);
  }
}

// ---------------- layer1 post-GEMM: h1 = sum_h relu(agg_h @ W1_h + b1_h) ----------------
// MFMA 16x16x32 f16; wave w covers rows m0..m0+15, cols 0..63; 10 heads accumulated.
__global__ __launch_bounds__(256) void k_ep1(const __half* __restrict__ aggh,
                                             const __half* __restrict__ w1t,
                                             const float* __restrict__ bias1,
                                             float* __restrict__ h1f, __half* __restrict__ h1h, int M){
  const int w = threadIdx.x >> 6, l = threadIdx.x & 63;
  const int m0 = blockIdx.x*64 + w*16;
  const int lr = l & 15, lk = l >> 4;
  int arow = m0 + lr; if (arow >= M) arow = M-1;
  float hsum[4][4];
  #pragma unroll
  for (int t=0;t<4;t++)
    #pragma unroll
    for (int j=0;j<4;j++) hsum[t][j] = 0.f;
  for (int h=0;h<10;h++){
    const __half* ap = aggh + (size_t)arow*640 + h*64;
    half8 a0 = *reinterpret_cast<const half8*>(ap + lk*8);
    half8 a1 = *reinterpret_cast<const half8*>(ap + 32 + lk*8);
    #pragma unroll
    for (int t=0;t<4;t++){
      const __half* bp = w1t + (size_t)(h*64 + t*16 + lr)*64 + lk*8;
      half8 b0 = *reinterpret_cast<const half8*>(bp);
      half8 b1 = *reinterpret_cast<const half8*>(bp + 32);
      floatx4 z = {0.f,0.f,0.f,0.f};
      z = __builtin_amdgcn_mfma_f32_16x16x32_f16(a0, b0, z, 0, 0, 0);
      z = __builtin_amdgcn_mfma_f32_16x16x32_f16(a1, b1, z, 0, 0, 0);
      float bb = bias1[h*64 + t*16 + lr];
      #pragma unroll
      for (int j=0;j<4;j++) hsum[t][j] += fmaxf(z[j] + bb, 0.f);
    }
  }
  #pragma unroll
  for (int t=0;t<4;t++)
    #pragma unroll
    for (int j=0;j<4;j++){
      int r = m0 + lk*4 + j;
      if (r < M){
        int c = t*16 + lr;
        h1f[(size_t)r*64 + c] = hsum[t][j];
        h1h[(size_t)r*64 + c] = __float2half(hsum[t][j]);
      }
    }
}

// ---------------- layer2 aggregation: gather 64-dim h1 rows (L2-resident) ----------------
__global__ __launch_bounds__(64) void k_edge2(const __half* __restrict__ h1h,
                                              const float* __restrict__ ge2,
                                              const float* __restrict__ er,
                                              const int* __restrict__ off,
                                              const int* __restrict__ srcs,
                                              __half* __restrict__ agg2h, int N){
  const int lane = threadIdx.x;
  const int n = blockIdx.x;
  if (n >= N) return;
  const int beg = off[n], end = off[n+1];
  const float ern = er[n];
  float mx = -INFINITY;
  for (int i=beg+lane; i<end; i+=64) mx = fmaxf(mx, ge2[i]);
  #pragma unroll
  for (int o=32;o>0;o>>=1) mx = fmaxf(mx, __shfl_xor(mx,o,64));
  const float m = leaky(mx + ern);
  float s = 0.f, acc = 0.f;
  for (int c0 = beg; c0 < end; c0 += 64){
    const bool vl = (c0 + lane < end);
    const int sv = vl ? srcs[c0 + lane] : 0;
    const float gv = vl ? ge2[c0 + lane] : -INFINITY;
    const float wv = __expf(leaky(gv + ern) - m);
    s += wv;
    const int cn = min(64, end - c0);
    for (int j = 0; j < cn; j += 4){
      const int nv = min(4, cn - j);
      float hv[4];
      #pragma unroll
      for (int jj=0;jj<4;jj++){
        if (jj < nv){
          int sj = __shfl(sv, j+jj, 64);
          hv[jj] = __half2float(h1h[(size_t)sj*64 + lane]);
        }
      }
      #pragma unroll
      for (int jj=0;jj<4;jj++){
        if (jj < nv) acc += __shfl(wv, j+jj, 64) * hv[jj];
      }
    }
  }
  s = wredsum(s);
  const float rs = (s > 0.f) ? 1.f/s : 0.f;
  agg2h[(size_t)n*64 + lane] = __float2half(acc * rs);
}

// ---------------- layer2 post-GEMM: h2 = relu(agg2 @ W2 + b2), fp32 [N,128] ----------------
__global__ __launch_bounds__(256) void k_l2(const __half* __restrict__ ah,
                                            const __half* __restrict__ wt,
                                            const float* __restrict__ bias2,
                                            float* __restrict__ h2, int M){
  const int w = threadIdx.x >> 6, l = threadIdx.x & 63;
  const int m0 = blockIdx.x*64 + w*16;
  const int c0 = blockIdx.y*64;
  const int lr = l & 15, lk = l >> 4;
  int arow = m0 + lr; if (arow >= M) arow = M-1;
  half8 a0 = *reinterpret_cast<const half8*>(ah + (size_t)arow*64 + lk*8);
  half8 a1 = *reinterpret_cast<const half8*>(ah + (size_t)arow*64 + 32 + lk*8);
  #pragma unroll
  for (int t=0;t<4;t++){
    const __half* bp = wt + (size_t)(c0 + t*16 + lr)*64 + lk*8;
    half8 b0 = *reinterpret_cast<const half8*>(bp);
    half8 b1 = *reinterpret_cast<const half8*>(bp + 32);
    floatx4 z = {0.f,0.f,0.f,0.f};
    z = __builtin_amdgcn_mfma_f32_16x16x32_f16(a0, b0, z, 0, 0, 0);
    z = __builtin_amdgcn_mfma_f32_16x16x32_f16(a1, b1, z, 0, 0, 0);
    float bb = bias2[c0 + t*16 + lr];
    #pragma unroll
    for (int j=0;j<4;j++){
      int r = m0 + lk*4 + j;
      if (r < M) h2[(size_t)r*128 + c0 + t*16 + lr] = fmaxf(z[j] + bb, 0.f);
    }
  }
}

// ---------------- per-graph max readout + 2-layer MLP ----------------
__device__ __forceinline__ int lowerb(const int* a, int n, int v){
  int lo=0, hi=n;
  while (lo < hi){ int mid=(lo+hi)>>1; if (a[mid] < v) lo=mid+1; else hi=mid; }
  return lo;
}

__global__ __launch_bounds__(128) void k_readout(const float* __restrict__ h2, const int* __restrict__ gid,
                                                 const float* __restrict__ lw1, const float* __restrict__ lb1,
                                                 const float* __restrict__ lw2, const float* __restrict__ lb2,
                                                 float* __restrict__ out, int N){
  int b = blockIdx.x, t = threadIdx.x;   // t = channel 0..127
  int lo = lowerb(gid, N, b), hi = lowerb(gid, N, b+1);
  float mx = -INFINITY;
  for (int n=lo; n<hi; ++n) mx = fmaxf(mx, h2[(size_t)n*128 + t]);
  if (hi == lo) mx = 0.f;   // empty-graph / isfinite safety
  __shared__ float gs[128];
  __shared__ float ys[128];
  gs[t] = mx;
  __syncthreads();
  float y = lb1[t];
  for (int k=0;k<128;k++) y += gs[k]*lw1[k*128 + t];
  y = fmaxf(y, 0.f);
  ys[t] = y * lw2[t];
  __syncthreads();
  for (int o=64;o>0;o>>=1){
    if (t < o) ys[t] += ys[t+o];
    __syncthreads();
  }
  if (t == 0) out[b] = fmaxf(ys[0] + lb2[0], 0.f);
}

extern "C" void kernel_launch(void* const* d_in, const int* in_sizes, int n_in,
                              void* d_out, int out_size, void* d_ws, size_t ws_size,
                              hipStream_t stream){
  const float* x   = (const float*)d_in[0];
  const int*   src = (const int*)d_in[1];
  const int*   dst = (const int*)d_in[2];
  const int*   gid = (const int*)d_in[3];
  const float* W1  = (const float*)d_in[4];
  const float* al1 = (const float*)d_in[5];
  const float* ar1 = (const float*)d_in[6];
  const float* b1  = (const float*)d_in[7];
  const float* W2  = (const float*)d_in[8];
  const float* al2 = (const float*)d_in[9];
  const float* ar2 = (const float*)d_in[10];
  const float* b2  = (const float*)d_in[11];
  const float* lw1 = (const float*)d_in[12];
  const float* lb1 = (const float*)d_in[13];
  const float* lw2 = (const float*)d_in[14];
  const float* lb2 = (const float*)d_in[15];
  float* out = (float*)d_out;

  const int N = in_sizes[0] / 64;
  const int E = in_sizes[1];
  const int G = out_size;

  char* w = (char*)d_ws;
  size_t p = 0;
  auto alloc = [&](size_t bytes)->char*{ char* r = w + p; p += (bytes + 255) & ~size_t(255); return r; };
  int*    deg   = (int*)alloc((size_t)N*4);
  int*    off   = (int*)alloc((size_t)(N+1)*4);
  int*    cur   = (int*)alloc((size_t)N*4);
  int*    srcs  = (int*)alloc((size_t)E*4);
  float*  el1   = (float*)alloc((size_t)N*10*4);
  float*  er1   = (float*)alloc((size_t)N*10*4);
  float*  ge16  = (float*)alloc((size_t)E*16*4);
  __half* xh    = (__half*)alloc((size_t)N*64*2);
  __half* w1t   = (__half*)alloc((size_t)640*64*2);
  __half* w2t   = (__half*)alloc((size_t)128*64*2);
  float*  qal1  = (float*)alloc((size_t)640*4);
  float*  qar1  = (float*)alloc((size_t)640*4);
  float*  qal2  = (float*)alloc((size_t)64*4);
  float*  qar2  = (float*)alloc((size_t)64*4);
  __half* aggh  = (__half*)alloc((size_t)N*640*2);
  float*  h1f   = (float*)alloc((size_t)N*64*4);
  __half* h1h   = (__half*)alloc((size_t)N*64*2);
  __half* agg2h = (__half*)alloc((size_t)N*64*2);
  float*  h2    = (float*)alloc((size_t)N*128*4);
  float*  el2 = el1;
  float*  er2 = er1;
  float*  ge2 = ge16;                  // E floats; ge16 dead after edge1

  const int nwB = (N + 3) / 4;
  const int gx  = (N + 63) / 64;
  const int prep_total = N*64 + 640*64 + 128*64 + 1280 + 128;

  k_zero   <<<dim3((N+255)/256), dim3(256), 0, stream>>>(deg, N);
  k_hist   <<<dim3((E+255)/256), dim3(256), 0, stream>>>(dst, deg, E);
  k_scan   <<<dim3(1),           dim3(1024),0, stream>>>(deg, off, cur, N);
  k_scatter<<<dim3((E+255)/256), dim3(256), 0, stream>>>(src, dst, cur, srcs, E);
  k_prep   <<<dim3((prep_total+255)/256), dim3(256), 0, stream>>>(x, W1, W2, al1, ar1, al2, ar2,
                                                                  xh, w1t, w2t, qal1, qar1, qal2, qar2, N*64);

  // layer 1: coefs from folded vectors; gather x-rows; project after aggregation
  k_coef1  <<<dim3(nwB), dim3(256), 0, stream>>>(x, qal1, qar1, el1, er1, N);
  k_gel1   <<<dim3((E*16+255)/256), dim3(256), 0, stream>>>(srcs, el1, ge16, E);
  k_edge1  <<<dim3(N), dim3(64), 0, stream>>>(xh, ge16, er1, off, srcs, aggh, N);
  k_ep1    <<<dim3(gx), dim3(256), 0, stream>>>(aggh, w1t, b1, h1f, h1h, N);

  // layer 2: same structure
  k_coef2  <<<dim3(nwB), dim3(256), 0, stream>>>(h1f, qal2, qar2, el2, er2, N);
  k_gel2   <<<dim3((E+255)/256), dim3(256), 0, stream>>>(srcs, el2, ge2, E);
  k_edge2  <<<dim3(N), dim3(64), 0, stream>>>(h1h, ge2, er2, off, srcs, agg2h, N);
  k_l2     <<<dim3(gx, 2), dim3(256), 0, stream>>>(agg2h, w2t, b2, h2, N);

  k_readout<<<dim3(G), dim3(128), 0, stream>>>(h2, gid, lw1, lb1, lw2, lb2, out, N);
}

// Round 10
// 254.090 us; speedup vs baseline: 1.1269x; 1.1269x over previous
//
#include <hip/hip_runtime.h>
#include <hip/hip_fp16.h>
#include <math.h>

typedef _Float16 half8 __attribute__((ext_vector_type(8)));
typedef float floatx4 __attribute__((ext_vector_type(4)));

__device__ __forceinline__ float leaky(float v){ return v > 0.f ? v : 0.2f*v; }

__device__ __forceinline__ float wredsum(float v){
  #pragma unroll
  for (int o=32;o>0;o>>=1) v += __shfl_xor(v,o,64);
  return v;
}

// ---------------- graph CSR build (by dst) ----------------
__global__ void k_zero(int* p, int n){
  int i = blockIdx.x*blockDim.x + threadIdx.x;
  if (i < n) p[i] = 0;
}

__global__ void k_hist(const int* __restrict__ dst, int* __restrict__ deg, int E){
  int i = blockIdx.x*blockDim.x + threadIdx.x;
  if (i < E) atomicAdd(&deg[dst[i]], 1);
}

__global__ __launch_bounds__(1024) void k_scan(const int* __restrict__ deg, int* __restrict__ off,
                                               int* __restrict__ cur, int N){
  __shared__ int part[1024];
  int t = threadIdx.x;
  int chunk = (N + 1023) >> 10;
  int c0 = t * chunk;
  int sum = 0;
  for (int i=0;i<chunk;i++){ int idx=c0+i; if (idx < N) sum += deg[idx]; }
  part[t] = sum;
  __syncthreads();
  for (int o=1;o<1024;o<<=1){
    int v = (t >= o) ? part[t-o] : 0;
    __syncthreads();
    part[t] += v;
    __syncthreads();
  }
  int run = part[t] - sum;   // exclusive prefix of this chunk
  for (int i=0;i<chunk;i++){
    int idx = c0+i;
    if (idx < N){ off[idx] = run; cur[idx] = run; run += deg[idx]; }
  }
  if (t == 1023) off[N] = part[1023];
}

__global__ void k_scatter(const int* __restrict__ src, const int* __restrict__ dst,
                          int* __restrict__ cur, int* __restrict__ srcs, int E){
  int i = blockIdx.x*blockDim.x + threadIdx.x;
  if (i < E){ int p = atomicAdd(&cur[dst[i]], 1); srcs[p] = src[i]; }
}

// ---------------- prep: fp16 casts, weight transposes, folded coef vectors ----------------
__global__ void k_prep(const float* __restrict__ x, const float* __restrict__ W1,
                       const float* __restrict__ W2,
                       const float* __restrict__ al1, const float* __restrict__ ar1,
                       const float* __restrict__ al2, const float* __restrict__ ar2,
                       __half* __restrict__ xh, __half* __restrict__ w1t, __half* __restrict__ w2t,
                       float* __restrict__ qal1, float* __restrict__ qar1,
                       float* __restrict__ qal2, float* __restrict__ qar2, int nx){
  int i = blockIdx.x*blockDim.x + threadIdx.x;
  if (i < nx){ xh[i] = __float2half(x[i]); return; }
  i -= nx;
  if (i < 640*64){ int c = i >> 6, k = i & 63; w1t[i] = __float2half(W1[k*640 + c]); return; }
  i -= 640*64;
  if (i < 128*64){ int c = i >> 6, k = i & 63; w2t[i] = __float2half(W2[k*128 + c]); return; }
  i -= 128*64;
  if (i < 1280){
    int which = i / 640; int j = i - which*640; int k = j / 10, h = j - k*10;
    const float* av = which ? ar1 : al1;
    float s = 0.f;
    for (int c=0;c<64;c++) s += W1[k*640 + h*64 + c] * av[h*64 + c];
    (which ? qar1 : qal1)[k*10 + h] = s;
    return;
  }
  i -= 1280;
  if (i < 128){
    int which = i >> 6; int k = i & 63;
    const float* av = which ? ar2 : al2;
    float s = 0.f;
    for (int c=0;c<128;c++) s += W2[k*128 + c] * av[c];
    (which ? qar2 : qal2)[k] = s;
    return;
  }
}

// ---------------- layer1 coefs via folded vectors ----------------
__global__ __launch_bounds__(256) void k_coef1(const float* __restrict__ x,
                                               const float* __restrict__ qal, const float* __restrict__ qar,
                                               float* __restrict__ el, float* __restrict__ er, int N){
  int n = blockIdx.x*4 + (threadIdx.x>>6);
  int lane = threadIdx.x & 63;
  if (n >= N) return;
  float xv = x[(size_t)n*64 + lane];
  #pragma unroll
  for (int h=0; h<10; h++){
    float pl = wredsum(xv * qal[lane*10 + h]);
    float pr = wredsum(xv * qar[lane*10 + h]);
    if (lane == 0){ el[n*10+h] = pl; er[n*10+h] = pr; }
  }
}

// ---------------- edge-logit pre-gather (CSR order) ----------------
__global__ void k_gel1(const int* __restrict__ srcs, const float* __restrict__ el,
                       float* __restrict__ ge16, int E){
  int t = blockIdx.x*blockDim.x + threadIdx.x;
  if (t >= E*16) return;
  int e = t >> 4, h = t & 15;
  int sv = srcs[e];
  ge16[t] = (h < 10) ? el[sv*10 + h] : -INFINITY;
}

__global__ void k_gel2(const int* __restrict__ srcs, const float* __restrict__ el,
                       float* __restrict__ ge2, int E){
  int e = blockIdx.x*blockDim.x + threadIdx.x;
  if (e < E) ge2[e] = el[srcs[e]];
}

// ---------------- layer1 aggregation via per-node MFMA ----------------
// agg[10x64] = softmaxW[10xdeg] @ X[degx64].  mfma 16x16x32 f16, K-chunks of 32 edges.
// A lane map: row(head)=l&15, k=(l>>4)*8+j.  B: col=l&15, same k.  D: col=l&15, row=(l>>4)*4+reg.
__global__ __launch_bounds__(64) void k_edge1(const __half* __restrict__ xh,
                                              const float* __restrict__ ge16,
                                              const float* __restrict__ er,
                                              const int* __restrict__ off,
                                              const int* __restrict__ srcs,
                                              __half* __restrict__ aggh, int N){
  const int l = threadIdx.x;
  const int n = blockIdx.x;
  const int lr = l & 15, lk = l >> 4;
  const int beg = off[n], end = off[n+1];
  const float erh = (lr < 10) ? er[n*10 + lr] : 0.f;
  // pass 1: per-head max (A-fragment layout; leaky monotone so max over raw logits)
  float m = -INFINITY;
  for (int c0 = beg; c0 < end; c0 += 32){
    #pragma unroll
    for (int j=0;j<8;j++){
      int p = c0 + lk*8 + j;
      float lg = (p < end) ? ge16[p*16 + lr] : -INFINITY;
      m = fmaxf(m, lg);
    }
  }
  m = fmaxf(m, __shfl_xor(m,16,64));
  m = fmaxf(m, __shfl_xor(m,32,64));
  m = (lr < 10) ? leaky(m + erh) : 0.f;   // finite for pad heads
  // pass 2: w = exp(leaky(el+er) - m) <= 1 (fp16-safe), MFMA accumulate
  float s = 0.f;
  floatx4 acc0 = {0.f,0.f,0.f,0.f}, acc1 = {0.f,0.f,0.f,0.f};
  floatx4 acc2 = {0.f,0.f,0.f,0.f}, acc3 = {0.f,0.f,0.f,0.f};
  for (int c0 = beg; c0 < end; c0 += 32){
    int ei = c0 + l;
    int sv = (ei < end) ? srcs[ei] : 0;
    half8 aw;
    #pragma unroll
    for (int j=0;j<8;j++){
      int p = c0 + lk*8 + j;
      float wv = 0.f;
      if (p < end && lr < 10){
        float lg = ge16[p*16 + lr];
        wv = __expf(leaky(lg + erh) - m);
      }
      aw[j] = (_Float16)wv;
      s += (float)aw[j];                 // denom from the same fp16 weights
    }
    int sj[8];
    #pragma unroll
    for (int j=0;j<8;j++) sj[j] = __shfl(sv, lk*8 + j, 64);
    half8 b0, b1, b2, b3;
    #pragma unroll
    for (int j=0;j<8;j++){
      const __half* rp = xh + (size_t)sj[j]*64;
      b0[j] = *(const _Float16*)(rp + lr);
      b1[j] = *(const _Float16*)(rp + 16 + lr);
      b2[j] = *(const _Float16*)(rp + 32 + lr);
      b3[j] = *(const _Float16*)(rp + 48 + lr);
    }
    acc0 = __builtin_amdgcn_mfma_f32_16x16x32_f16(aw, b0, acc0, 0, 0, 0);
    acc1 = __builtin_amdgcn_mfma_f32_16x16x32_f16(aw, b1, acc1, 0, 0, 0);
    acc2 = __builtin_amdgcn_mfma_f32_16x16x32_f16(aw, b2, acc2, 0, 0, 0);
    acc3 = __builtin_amdgcn_mfma_f32_16x16x32_f16(aw, b3, acc3, 0, 0, 0);
  }
  s += __shfl_xor(s,16,64);
  s += __shfl_xor(s,32,64);
  const float rs = (lr < 10 && s > 0.f) ? 1.f/s : 0.f;
  #pragma unroll
  for (int j=0;j<4;j++){
    int h = lk*4 + j;
    float rj = __shfl(rs, h, 64);   // lane h has lr==h
    if (h < 10){
      __half* op = aggh + (size_t)n*640 + h*64;
      op[lr]      = __float2half(acc0[j] * rj);
      op[16 + lr] = __float2half(acc1[j] * rj);
      op[32 + lr] = __float2half(acc2[j] * rj);
      op[48 + lr] = __float2half(acc3[j] * rj);
    }
  }
}

// ---------------- layer1 post-GEMM + fused layer2 coefs ----------------
// h1 = sum_h relu(agg_h @ W1_h + b1_h); el2[n]=h1[n,:]*qal2; er2 likewise.
__global__ __launch_bounds__(256) void k_ep1(const __half* __restrict__ aggh,
                                             const __half* __restrict__ w1t,
                                             const float* __restrict__ bias1,
                                             __half* __restrict__ h1h,
                                             const float* __restrict__ qal2,
                                             const float* __restrict__ qar2,
                                             float* __restrict__ el2, float* __restrict__ er2, int M){
  const int w = threadIdx.x >> 6, l = threadIdx.x & 63;
  const int m0 = blockIdx.x*64 + w*16;
  const int lr = l & 15, lk = l >> 4;
  int arow = m0 + lr; if (arow >= M) arow = M-1;
  float hsum[4][4];
  #pragma unroll
  for (int t=0;t<4;t++)
    #pragma unroll
    for (int j=0;j<4;j++) hsum[t][j] = 0.f;
  for (int h=0;h<10;h++){
    const __half* ap = aggh + (size_t)arow*640 + h*64;
    half8 a0 = *reinterpret_cast<const half8*>(ap + lk*8);
    half8 a1 = *reinterpret_cast<const half8*>(ap + 32 + lk*8);
    #pragma unroll
    for (int t=0;t<4;t++){
      const __half* bp = w1t + (size_t)(h*64 + t*16 + lr)*64 + lk*8;
      half8 b0 = *reinterpret_cast<const half8*>(bp);
      half8 b1 = *reinterpret_cast<const half8*>(bp + 32);
      floatx4 z = {0.f,0.f,0.f,0.f};
      z = __builtin_amdgcn_mfma_f32_16x16x32_f16(a0, b0, z, 0, 0, 0);
      z = __builtin_amdgcn_mfma_f32_16x16x32_f16(a1, b1, z, 0, 0, 0);
      float bb = bias1[h*64 + t*16 + lr];
      #pragma unroll
      for (int j=0;j<4;j++) hsum[t][j] += fmaxf(z[j] + bb, 0.f);
    }
  }
  // store h1 (fp16)
  #pragma unroll
  for (int t=0;t<4;t++)
    #pragma unroll
    for (int j=0;j<4;j++){
      int r = m0 + lk*4 + j;
      if (r < M) h1h[(size_t)r*64 + t*16 + lr] = __float2half(hsum[t][j]);
    }
  // fused layer-2 coefs from in-register h1 rows
  float pl[4] = {0,0,0,0}, pr[4] = {0,0,0,0};
  #pragma unroll
  for (int t=0;t<4;t++){
    float qa = qal2[t*16 + lr];
    float qr = qar2[t*16 + lr];
    #pragma unroll
    for (int j=0;j<4;j++){ pl[j] += hsum[t][j]*qa; pr[j] += hsum[t][j]*qr; }
  }
  #pragma unroll
  for (int o=1;o<16;o<<=1)
    #pragma unroll
    for (int j=0;j<4;j++){ pl[j] += __shfl_xor(pl[j],o,64); pr[j] += __shfl_xor(pr[j],o,64); }
  if (lr == 0){
    #pragma unroll
    for (int j=0;j<4;j++){
      int r = m0 + lk*4 + j;
      if (r < M){ el2[r] = pl[j]; er2[r] = pr[j]; }
    }
  }
}

// ---------------- layer2 aggregation (no max pass; fp32 exp is range-safe) ----------------
__global__ __launch_bounds__(64) void k_edge2(const __half* __restrict__ h1h,
                                              const float* __restrict__ ge2,
                                              const float* __restrict__ er,
                                              const int* __restrict__ off,
                                              const int* __restrict__ srcs,
                                              __half* __restrict__ agg2h, int N){
  const int lane = threadIdx.x;
  const int n = blockIdx.x;
  const int beg = off[n], end = off[n+1];
  const float ern = er[n];
  float s = 0.f, acc = 0.f;
  for (int c0 = beg; c0 < end; c0 += 64){
    const bool vl = (c0 + lane < end);
    const int sv = vl ? srcs[c0 + lane] : 0;
    const float gv = vl ? ge2[c0 + lane] : -INFINITY;
    const float wv = __expf(leaky(gv + ern));   // softmax shift-invariant; pad -> 0
    s += wv;
    const int cn = min(64, end - c0);
    for (int j = 0; j < cn; j += 8){
      const int nv = min(8, cn - j);
      float hv[8], wj[8];
      #pragma unroll
      for (int jj=0;jj<8;jj++){
        if (jj < nv){
          int sj = __shfl(sv, j+jj, 64);
          hv[jj] = __half2float(h1h[(size_t)sj*64 + lane]);
          wj[jj] = __shfl(wv, j+jj, 64);
        }
      }
      #pragma unroll
      for (int jj=0;jj<8;jj++) if (jj < nv) acc += wj[jj]*hv[jj];
    }
  }
  s = wredsum(s);
  const float rs = (s > 0.f) ? 1.f/s : 0.f;
  agg2h[(size_t)n*64 + lane] = __float2half(acc * rs);
}

// ---------------- layer2 post-GEMM: h2 = relu(agg2 @ W2 + b2), fp32 [N,128] ----------------
__global__ __launch_bounds__(256) void k_l2(const __half* __restrict__ ah,
                                            const __half* __restrict__ wt,
                                            const float* __restrict__ bias2,
                                            float* __restrict__ h2, int M){
  const int w = threadIdx.x >> 6, l = threadIdx.x & 63;
  const int m0 = blockIdx.x*64 + w*16;
  const int c0 = blockIdx.y*64;
  const int lr = l & 15, lk = l >> 4;
  int arow = m0 + lr; if (arow >= M) arow = M-1;
  half8 a0 = *reinterpret_cast<const half8*>(ah + (size_t)arow*64 + lk*8);
  half8 a1 = *reinterpret_cast<const half8*>(ah + (size_t)arow*64 + 32 + lk*8);
  #pragma unroll
  for (int t=0;t<4;t++){
    const __half* bp = wt + (size_t)(c0 + t*16 + lr)*64 + lk*8;
    half8 b0 = *reinterpret_cast<const half8*>(bp);
    half8 b1 = *reinterpret_cast<const half8*>(bp + 32);
    floatx4 z = {0.f,0.f,0.f,0.f};
    z = __builtin_amdgcn_mfma_f32_16x16x32_f16(a0, b0, z, 0, 0, 0);
    z = __builtin_amdgcn_mfma_f32_16x16x32_f16(a1, b1, z, 0, 0, 0);
    float bb = bias2[c0 + t*16 + lr];
    #pragma unroll
    for (int j=0;j<4;j++){
      int r = m0 + lk*4 + j;
      if (r < M) h2[(size_t)r*128 + c0 + t*16 + lr] = fmaxf(z[j] + bb, 0.f);
    }
  }
}

// ---------------- per-graph max readout + 2-layer MLP ----------------
__device__ __forceinline__ int lowerb(const int* a, int n, int v){
  int lo=0, hi=n;
  while (lo < hi){ int mid=(lo+hi)>>1; if (a[mid] < v) lo=mid+1; else hi=mid; }
  return lo;
}

__global__ __launch_bounds__(128) void k_readout(const float* __restrict__ h2, const int* __restrict__ gid,
                                                 const float* __restrict__ lw1, const float* __restrict__ lb1,
                                                 const float* __restrict__ lw2, const float* __restrict__ lb2,
                                                 float* __restrict__ out, int N){
  int b = blockIdx.x, t = threadIdx.x;   // t = channel 0..127
  int lo = lowerb(gid, N, b), hi = lowerb(gid, N, b+1);
  float mx = -INFINITY;
  for (int n=lo; n<hi; ++n) mx = fmaxf(mx, h2[(size_t)n*128 + t]);
  if (hi == lo) mx = 0.f;   // empty-graph / isfinite safety
  __shared__ float gs[128];
  __shared__ float ys[128];
  gs[t] = mx;
  __syncthreads();
  float y = lb1[t];
  for (int k=0;k<128;k++) y += gs[k]*lw1[k*128 + t];
  y = fmaxf(y, 0.f);
  ys[t] = y * lw2[t];
  __syncthreads();
  for (int o=64;o>0;o>>=1){
    if (t < o) ys[t] += ys[t+o];
    __syncthreads();
  }
  if (t == 0) out[b] = fmaxf(ys[0] + lb2[0], 0.f);
}

extern "C" void kernel_launch(void* const* d_in, const int* in_sizes, int n_in,
                              void* d_out, int out_size, void* d_ws, size_t ws_size,
                              hipStream_t stream){
  const float* x   = (const float*)d_in[0];
  const int*   src = (const int*)d_in[1];
  const int*   dst = (const int*)d_in[2];
  const int*   gid = (const int*)d_in[3];
  const float* W1  = (const float*)d_in[4];
  const float* al1 = (const float*)d_in[5];
  const float* ar1 = (const float*)d_in[6];
  const float* b1  = (const float*)d_in[7];
  const float* W2  = (const float*)d_in[8];
  const float* al2 = (const float*)d_in[9];
  const float* ar2 = (const float*)d_in[10];
  const float* b2  = (const float*)d_in[11];
  const float* lw1 = (const float*)d_in[12];
  const float* lb1 = (const float*)d_in[13];
  const float* lw2 = (const float*)d_in[14];
  const float* lb2 = (const float*)d_in[15];
  float* out = (float*)d_out;

  const int N = in_sizes[0] / 64;
  const int E = in_sizes[1];
  const int G = out_size;

  char* w = (char*)d_ws;
  size_t p = 0;
  auto alloc = [&](size_t bytes)->char*{ char* r = w + p; p += (bytes + 255) & ~size_t(255); return r; };
  int*    deg   = (int*)alloc((size_t)N*4);
  int*    off   = (int*)alloc((size_t)(N+1)*4);
  int*    cur   = (int*)alloc((size_t)N*4);
  int*    srcs  = (int*)alloc((size_t)E*4);
  float*  el1   = (float*)alloc((size_t)N*10*4);
  float*  er1   = (float*)alloc((size_t)N*10*4);
  float*  ge16  = (float*)alloc((size_t)E*16*4);
  __half* xh    = (__half*)alloc((size_t)N*64*2);
  __half* w1t   = (__half*)alloc((size_t)640*64*2);
  __half* w2t   = (__half*)alloc((size_t)128*64*2);
  float*  qal1  = (float*)alloc((size_t)640*4);
  float*  qar1  = (float*)alloc((size_t)640*4);
  float*  qal2  = (float*)alloc((size_t)64*4);
  float*  qar2  = (float*)alloc((size_t)64*4);
  __half* aggh  = (__half*)alloc((size_t)N*640*2);
  __half* h1h   = (__half*)alloc((size_t)N*64*2);
  __half* agg2h = (__half*)alloc((size_t)N*64*2);
  float*  h2    = (float*)alloc((size_t)N*128*4);
  float*  el2 = el1;
  float*  er2 = er1;
  float*  ge2 = ge16;                  // E floats; ge16 dead after edge1

  const int nwB = (N + 3) / 4;
  const int gx  = (N + 63) / 64;
  const int prep_total = N*64 + 640*64 + 128*64 + 1280 + 128;

  k_zero   <<<dim3((N+255)/256), dim3(256), 0, stream>>>(deg, N);
  k_hist   <<<dim3((E+255)/256), dim3(256), 0, stream>>>(dst, deg, E);
  k_scan   <<<dim3(1),           dim3(1024),0, stream>>>(deg, off, cur, N);
  k_scatter<<<dim3((E+255)/256), dim3(256), 0, stream>>>(src, dst, cur, srcs, E);
  k_prep   <<<dim3((prep_total+255)/256), dim3(256), 0, stream>>>(x, W1, W2, al1, ar1, al2, ar2,
                                                                  xh, w1t, w2t, qal1, qar1, qal2, qar2, N*64);

  // layer 1
  k_coef1  <<<dim3(nwB), dim3(256), 0, stream>>>(x, qal1, qar1, el1, er1, N);
  k_gel1   <<<dim3((E*16+255)/256), dim3(256), 0, stream>>>(srcs, el1, ge16, E);
  k_edge1  <<<dim3(N), dim3(64), 0, stream>>>(xh, ge16, er1, off, srcs, aggh, N);
  k_ep1    <<<dim3(gx), dim3(256), 0, stream>>>(aggh, w1t, b1, h1h, qal2, qar2, el2, er2, N);

  // layer 2
  k_gel2   <<<dim3((E+255)/256), dim3(256), 0, stream>>>(srcs, el2, ge2, E);
  k_edge2  <<<dim3(N), dim3(64), 0, stream>>>(h1h, ge2, er2, off, srcs, agg2h, N);
  k_l2     <<<dim3(gx, 2), dim3(256), 0, stream>>>(agg2h, w2t, b2, h2, N);

  k_readout<<<dim3(G), dim3(128), 0, stream>>>(h2, gid, lw1, lb1, lw2, lb2, out, N);
}

// Round 11
// 232.352 us; speedup vs baseline: 1.2323x; 1.0936x over previous
//
#include <hip/hip_runtime.h>
#include <hip/hip_fp16.h>
#include <math.h>

typedef _Float16 half8 __attribute__((ext_vector_type(8)));
typedef float floatx4 __attribute__((ext_vector_type(4)));

__device__ __forceinline__ float leaky(float v){ return v > 0.f ? v : 0.2f*v; }

__device__ __forceinline__ float wredsum(float v){
  #pragma unroll
  for (int o=32;o>0;o>>=1) v += __shfl_xor(v,o,64);
  return v;
}

// ---------------- graph CSR build (by dst) ----------------
__global__ void k_zero(int* p, int n){
  int i = blockIdx.x*blockDim.x + threadIdx.x;
  if (i < n) p[i] = 0;
}

__global__ void k_hist(const int* __restrict__ dst, int* __restrict__ deg, int E){
  int i = blockIdx.x*blockDim.x + threadIdx.x;
  if (i < E) atomicAdd(&deg[dst[i]], 1);
}

__global__ __launch_bounds__(1024) void k_scan(const int* __restrict__ deg, int* __restrict__ off,
                                               int* __restrict__ cur, int N){
  __shared__ int part[1024];
  int t = threadIdx.x;
  int chunk = (N + 1023) >> 10;
  int c0 = t * chunk;
  int sum = 0;
  for (int i=0;i<chunk;i++){ int idx=c0+i; if (idx < N) sum += deg[idx]; }
  part[t] = sum;
  __syncthreads();
  for (int o=1;o<1024;o<<=1){
    int v = (t >= o) ? part[t-o] : 0;
    __syncthreads();
    part[t] += v;
    __syncthreads();
  }
  int run = part[t] - sum;   // exclusive prefix of this chunk
  for (int i=0;i<chunk;i++){
    int idx = c0+i;
    if (idx < N){ off[idx] = run; cur[idx] = run; run += deg[idx]; }
  }
  if (t == 1023) off[N] = part[1023];
}

__global__ void k_scatter(const int* __restrict__ src, const int* __restrict__ dst,
                          int* __restrict__ cur, int* __restrict__ srcs, int E){
  int i = blockIdx.x*blockDim.x + threadIdx.x;
  if (i < E){ int p = atomicAdd(&cur[dst[i]], 1); srcs[p] = src[i]; }
}

// ---------------- prep: fp16 casts, weight transposes, folded coef vectors ----------------
__global__ void k_prep(const float* __restrict__ x, const float* __restrict__ W1,
                       const float* __restrict__ W2,
                       const float* __restrict__ al1, const float* __restrict__ ar1,
                       const float* __restrict__ al2, const float* __restrict__ ar2,
                       __half* __restrict__ xh, __half* __restrict__ w1t, __half* __restrict__ w2t,
                       float* __restrict__ qal1, float* __restrict__ qar1,
                       float* __restrict__ qal2, float* __restrict__ qar2, int nx){
  int i = blockIdx.x*blockDim.x + threadIdx.x;
  if (i < nx){ xh[i] = __float2half(x[i]); return; }
  i -= nx;
  if (i < 640*64){ int c = i >> 6, k = i & 63; w1t[i] = __float2half(W1[k*640 + c]); return; }
  i -= 640*64;
  if (i < 128*64){ int c = i >> 6, k = i & 63; w2t[i] = __float2half(W2[k*128 + c]); return; }
  i -= 128*64;
  if (i < 1280){
    int which = i / 640; int j = i - which*640; int k = j / 10, h = j - k*10;
    const float* av = which ? ar1 : al1;
    float s = 0.f;
    for (int c=0;c<64;c++) s += W1[k*640 + h*64 + c] * av[h*64 + c];
    (which ? qar1 : qal1)[k*10 + h] = s;
    return;
  }
  i -= 1280;
  if (i < 128){
    int which = i >> 6; int k = i & 63;
    const float* av = which ? ar2 : al2;
    float s = 0.f;
    for (int c=0;c<128;c++) s += W2[k*128 + c] * av[c];
    (which ? qar2 : qal2)[k] = s;
    return;
  }
}

// ---------------- layer1 coefs via folded vectors ----------------
__global__ __launch_bounds__(256) void k_coef1(const float* __restrict__ x,
                                               const float* __restrict__ qal, const float* __restrict__ qar,
                                               float* __restrict__ el, float* __restrict__ er, int N){
  int n = blockIdx.x*4 + (threadIdx.x>>6);
  int lane = threadIdx.x & 63;
  if (n >= N) return;
  float xv = x[(size_t)n*64 + lane];
  #pragma unroll
  for (int h=0; h<10; h++){
    float pl = wredsum(xv * qal[lane*10 + h]);
    float pr = wredsum(xv * qar[lane*10 + h]);
    if (lane == 0){ el[n*10+h] = pl; er[n*10+h] = pr; }
  }
}

// ---------------- edge-logit pre-gather (CSR order) ----------------
__global__ void k_gel1(const int* __restrict__ srcs, const float* __restrict__ el,
                       float* __restrict__ ge16, int E){
  int t = blockIdx.x*blockDim.x + threadIdx.x;
  if (t >= E*16) return;
  int e = t >> 4, h = t & 15;
  int sv = srcs[e];
  ge16[t] = (h < 10) ? el[sv*10 + h] : -INFINITY;
}

__global__ void k_gel2(const int* __restrict__ srcs, const float* __restrict__ el,
                       float* __restrict__ ge2, int E){
  int e = blockIdx.x*blockDim.x + threadIdx.x;
  if (e < E) ge2[e] = el[srcs[e]];
}

// ---------------- layer1 aggregation via per-node MFMA ----------------
__global__ __launch_bounds__(64) void k_edge1(const __half* __restrict__ xh,
                                              const float* __restrict__ ge16,
                                              const float* __restrict__ er,
                                              const int* __restrict__ off,
                                              const int* __restrict__ srcs,
                                              __half* __restrict__ aggh, int N){
  const int l = threadIdx.x;
  const int n = blockIdx.x;
  const int lr = l & 15, lk = l >> 4;
  const int beg = off[n], end = off[n+1];
  const float erh = (lr < 10) ? er[n*10 + lr] : 0.f;
  float m = -INFINITY;
  for (int c0 = beg; c0 < end; c0 += 32){
    #pragma unroll
    for (int j=0;j<8;j++){
      int p = c0 + lk*8 + j;
      float lg = (p < end) ? ge16[p*16 + lr] : -INFINITY;
      m = fmaxf(m, lg);
    }
  }
  m = fmaxf(m, __shfl_xor(m,16,64));
  m = fmaxf(m, __shfl_xor(m,32,64));
  m = (lr < 10) ? leaky(m + erh) : 0.f;
  float s = 0.f;
  floatx4 acc0 = {0.f,0.f,0.f,0.f}, acc1 = {0.f,0.f,0.f,0.f};
  floatx4 acc2 = {0.f,0.f,0.f,0.f}, acc3 = {0.f,0.f,0.f,0.f};
  for (int c0 = beg; c0 < end; c0 += 32){
    int ei = c0 + l;
    int sv = (ei < end) ? srcs[ei] : 0;
    half8 aw;
    #pragma unroll
    for (int j=0;j<8;j++){
      int p = c0 + lk*8 + j;
      float wv = 0.f;
      if (p < end && lr < 10){
        float lg = ge16[p*16 + lr];
        wv = __expf(leaky(lg + erh) - m);
      }
      aw[j] = (_Float16)wv;
      s += (float)aw[j];
    }
    int sj[8];
    #pragma unroll
    for (int j=0;j<8;j++) sj[j] = __shfl(sv, lk*8 + j, 64);
    half8 b0, b1, b2, b3;
    #pragma unroll
    for (int j=0;j<8;j++){
      const __half* rp = xh + (size_t)sj[j]*64;
      b0[j] = *(const _Float16*)(rp + lr);
      b1[j] = *(const _Float16*)(rp + 16 + lr);
      b2[j] = *(const _Float16*)(rp + 32 + lr);
      b3[j] = *(const _Float16*)(rp + 48 + lr);
    }
    acc0 = __builtin_amdgcn_mfma_f32_16x16x32_f16(aw, b0, acc0, 0, 0, 0);
    acc1 = __builtin_amdgcn_mfma_f32_16x16x32_f16(aw, b1, acc1, 0, 0, 0);
    acc2 = __builtin_amdgcn_mfma_f32_16x16x32_f16(aw, b2, acc2, 0, 0, 0);
    acc3 = __builtin_amdgcn_mfma_f32_16x16x32_f16(aw, b3, acc3, 0, 0, 0);
  }
  s += __shfl_xor(s,16,64);
  s += __shfl_xor(s,32,64);
  const float rs = (lr < 10 && s > 0.f) ? 1.f/s : 0.f;
  #pragma unroll
  for (int j=0;j<4;j++){
    int h = lk*4 + j;
    float rj = __shfl(rs, h, 64);
    if (h < 10){
      __half* op = aggh + (size_t)n*640 + h*64;
      op[lr]      = __float2half(acc0[j] * rj);
      op[16 + lr] = __float2half(acc1[j] * rj);
      op[32 + lr] = __float2half(acc2[j] * rj);
      op[48 + lr] = __float2half(acc3[j] * rj);
    }
  }
}

// ---------------- layer1 post-GEMM + fused layer2 coefs ----------------
__global__ __launch_bounds__(256) void k_ep1(const __half* __restrict__ aggh,
                                             const __half* __restrict__ w1t,
                                             const float* __restrict__ bias1,
                                             __half* __restrict__ h1h,
                                             const float* __restrict__ qal2,
                                             const float* __restrict__ qar2,
                                             float* __restrict__ el2, float* __restrict__ er2, int M){
  const int w = threadIdx.x >> 6, l = threadIdx.x & 63;
  const int m0 = blockIdx.x*64 + w*16;
  const int lr = l & 15, lk = l >> 4;
  int arow = m0 + lr; if (arow >= M) arow = M-1;
  float hsum[4][4];
  #pragma unroll
  for (int t=0;t<4;t++)
    #pragma unroll
    for (int j=0;j<4;j++) hsum[t][j] = 0.f;
  for (int h=0;h<10;h++){
    const __half* ap = aggh + (size_t)arow*640 + h*64;
    half8 a0 = *reinterpret_cast<const half8*>(ap + lk*8);
    half8 a1 = *reinterpret_cast<const half8*>(ap + 32 + lk*8);
    #pragma unroll
    for (int t=0;t<4;t++){
      const __half* bp = w1t + (size_t)(h*64 + t*16 + lr)*64 + lk*8;
      half8 b0 = *reinterpret_cast<const half8*>(bp);
      half8 b1 = *reinterpret_cast<const half8*>(bp + 32);
      floatx4 z = {0.f,0.f,0.f,0.f};
      z = __builtin_amdgcn_mfma_f32_16x16x32_f16(a0, b0, z, 0, 0, 0);
      z = __builtin_amdgcn_mfma_f32_16x16x32_f16(a1, b1, z, 0, 0, 0);
      float bb = bias1[h*64 + t*16 + lr];
      #pragma unroll
      for (int j=0;j<4;j++) hsum[t][j] += fmaxf(z[j] + bb, 0.f);
    }
  }
  #pragma unroll
  for (int t=0;t<4;t++)
    #pragma unroll
    for (int j=0;j<4;j++){
      int r = m0 + lk*4 + j;
      if (r < M) h1h[(size_t)r*64 + t*16 + lr] = __float2half(hsum[t][j]);
    }
  float pl[4] = {0,0,0,0}, pr[4] = {0,0,0,0};
  #pragma unroll
  for (int t=0;t<4;t++){
    float qa = qal2[t*16 + lr];
    float qr = qar2[t*16 + lr];
    #pragma unroll
    for (int j=0;j<4;j++){ pl[j] += hsum[t][j]*qa; pr[j] += hsum[t][j]*qr; }
  }
  #pragma unroll
  for (int o=1;o<16;o<<=1)
    #pragma unroll
    for (int j=0;j<4;j++){ pl[j] += __shfl_xor(pl[j],o,64); pr[j] += __shfl_xor(pr[j],o,64); }
  if (lr == 0){
    #pragma unroll
    for (int j=0;j<4;j++){
      int r = m0 + lk*4 + j;
      if (r < M){ el2[r] = pl[j]; er2[r] = pr[j]; }
    }
  }
}

// ---------------- layer2 aggregation (no max pass; fp32 exp is range-safe) ----------------
__global__ __launch_bounds__(64) void k_edge2(const __half* __restrict__ h1h,
                                              const float* __restrict__ ge2,
                                              const float* __restrict__ er,
                                              const int* __restrict__ off,
                                              const int* __restrict__ srcs,
                                              __half* __restrict__ agg2h, int N){
  const int lane = threadIdx.x;
  const int n = blockIdx.x;
  const int beg = off[n], end = off[n+1];
  const float ern = er[n];
  float s = 0.f, acc = 0.f;
  for (int c0 = beg; c0 < end; c0 += 64){
    const bool vl = (c0 + lane < end);
    const int sv = vl ? srcs[c0 + lane] : 0;
    const float gv = vl ? ge2[c0 + lane] : -INFINITY;
    const float wv = __expf(leaky(gv + ern));
    s += wv;
    const int cn = min(64, end - c0);
    for (int j = 0; j < cn; j += 8){
      const int nv = min(8, cn - j);
      float hv[8], wj[8];
      #pragma unroll
      for (int jj=0;jj<8;jj++){
        if (jj < nv){
          int sj = __shfl(sv, j+jj, 64);
          hv[jj] = __half2float(h1h[(size_t)sj*64 + lane]);
          wj[jj] = __shfl(wv, j+jj, 64);
        }
      }
      #pragma unroll
      for (int jj=0;jj<8;jj++) if (jj < nv) acc += wj[jj]*hv[jj];
    }
  }
  s = wredsum(s);
  const float rs = (s > 0.f) ? 1.f/s : 0.f;
  agg2h[(size_t)n*64 + lane] = __float2half(acc * rs);
}

// ---------------- layer2 post-GEMM: h2 = relu(agg2 @ W2 + b2), fp32 [N,128] ----------------
__global__ __launch_bounds__(256) void k_l2(const __half* __restrict__ ah,
                                            const __half* __restrict__ wt,
                                            const float* __restrict__ bias2,
                                            float* __restrict__ h2, int M){
  const int w = threadIdx.x >> 6, l = threadIdx.x & 63;
  const int m0 = blockIdx.x*64 + w*16;
  const int c0 = blockIdx.y*64;
  const int lr = l & 15, lk = l >> 4;
  int arow = m0 + lr; if (arow >= M) arow = M-1;
  half8 a0 = *reinterpret_cast<const half8*>(ah + (size_t)arow*64 + lk*8);
  half8 a1 = *reinterpret_cast<const half8*>(ah + (size_t)arow*64 + 32 + lk*8);
  #pragma unroll
  for (int t=0;t<4;t++){
    const __half* bp = wt + (size_t)(c0 + t*16 + lr)*64 + lk*8;
    half8 b0 = *reinterpret_cast<const half8*>(bp);
    half8 b1 = *reinterpret_cast<const half8*>(bp + 32);
    floatx4 z = {0.f,0.f,0.f,0.f};
    z = __builtin_amdgcn_mfma_f32_16x16x32_f16(a0, b0, z, 0, 0, 0);
    z = __builtin_amdgcn_mfma_f32_16x16x32_f16(a1, b1, z, 0, 0, 0);
    float bb = bias2[c0 + t*16 + lr];
    #pragma unroll
    for (int j=0;j<4;j++){
      int r = m0 + lk*4 + j;
      if (r < M) h2[(size_t)r*128 + c0 + t*16 + lr] = fmaxf(z[j] + bb, 0.f);
    }
  }
}

// ---------------- node-parallel segmented max (h2 >= 0; int-bit atomicMax exact) ----------------
// Block covers 64 nodes x 128 channels with 256 threads (c = tid&127, parity q = tid>>7).
// gid sorted -> register run-max per gid run, atomic flush on run change (~1-2 per thread).
__global__ __launch_bounds__(256) void k_gmax(const float* __restrict__ h2, const int* __restrict__ gid,
                                              int* __restrict__ g, int N){
  const int c = threadIdx.x & 127;
  const int q = threadIdx.x >> 7;
  int n = blockIdx.x*64 + q;
  const int nend = min(blockIdx.x*64 + 64, N);
  if (n >= nend) return;
  int curg = gid[n];
  float mx = 0.f;
  for (; n < nend; n += 2){
    int gg = gid[n];
    if (gg != curg){
      atomicMax(&g[curg*128 + c], __float_as_int(mx));
      curg = gg; mx = 0.f;
    }
    mx = fmaxf(mx, h2[(size_t)n*128 + c]);
  }
  atomicMax(&g[curg*128 + c], __float_as_int(mx));
}

// ---------------- per-graph 2-layer MLP ----------------
__global__ __launch_bounds__(128) void k_mlp(const int* __restrict__ g,
                                             const float* __restrict__ lw1, const float* __restrict__ lb1,
                                             const float* __restrict__ lw2, const float* __restrict__ lb2,
                                             float* __restrict__ out){
  int b = blockIdx.x, t = threadIdx.x;
  __shared__ float gs[128];
  __shared__ float ys[128];
  gs[t] = __int_as_float(g[b*128 + t]);
  __syncthreads();
  float y = lb1[t];
  for (int k=0;k<128;k++) y += gs[k]*lw1[k*128 + t];
  y = fmaxf(y, 0.f);
  ys[t] = y * lw2[t];
  __syncthreads();
  for (int o=64;o>0;o>>=1){
    if (t < o) ys[t] += ys[t+o];
    __syncthreads();
  }
  if (t == 0) out[b] = fmaxf(ys[0] + lb2[0], 0.f);
}

extern "C" void kernel_launch(void* const* d_in, const int* in_sizes, int n_in,
                              void* d_out, int out_size, void* d_ws, size_t ws_size,
                              hipStream_t stream){
  const float* x   = (const float*)d_in[0];
  const int*   src = (const int*)d_in[1];
  const int*   dst = (const int*)d_in[2];
  const int*   gid = (const int*)d_in[3];
  const float* W1  = (const float*)d_in[4];
  const float* al1 = (const float*)d_in[5];
  const float* ar1 = (const float*)d_in[6];
  const float* b1  = (const float*)d_in[7];
  const float* W2  = (const float*)d_in[8];
  const float* al2 = (const float*)d_in[9];
  const float* ar2 = (const float*)d_in[10];
  const float* b2  = (const float*)d_in[11];
  const float* lw1 = (const float*)d_in[12];
  const float* lb1 = (const float*)d_in[13];
  const float* lw2 = (const float*)d_in[14];
  const float* lb2 = (const float*)d_in[15];
  float* out = (float*)d_out;

  const int N = in_sizes[0] / 64;
  const int E = in_sizes[1];
  const int G = out_size;

  char* w = (char*)d_ws;
  size_t p = 0;
  auto alloc = [&](size_t bytes)->char*{ char* r = w + p; p += (bytes + 255) & ~size_t(255); return r; };
  int*    deg   = (int*)alloc((size_t)N*4);
  int*    off   = (int*)alloc((size_t)(N+1)*4);
  int*    cur   = (int*)alloc((size_t)N*4);
  int*    srcs  = (int*)alloc((size_t)E*4);
  float*  el1   = (float*)alloc((size_t)N*10*4);
  float*  er1   = (float*)alloc((size_t)N*10*4);
  float*  ge16  = (float*)alloc((size_t)E*16*4);
  __half* xh    = (__half*)alloc((size_t)N*64*2);
  __half* w1t   = (__half*)alloc((size_t)640*64*2);
  __half* w2t   = (__half*)alloc((size_t)128*64*2);
  float*  qal1  = (float*)alloc((size_t)640*4);
  float*  qar1  = (float*)alloc((size_t)640*4);
  float*  qal2  = (float*)alloc((size_t)64*4);
  float*  qar2  = (float*)alloc((size_t)64*4);
  __half* aggh  = (__half*)alloc((size_t)N*640*2);
  __half* h1h   = (__half*)alloc((size_t)N*64*2);
  __half* agg2h = (__half*)alloc((size_t)N*64*2);
  float*  h2    = (float*)alloc((size_t)N*128*4);
  int*    gbuf  = (int*)alloc((size_t)G*128*4);
  float*  el2 = el1;
  float*  er2 = er1;
  float*  ge2 = ge16;                  // E floats; ge16 dead after edge1

  const int nwB = (N + 3) / 4;
  const int gx  = (N + 63) / 64;
  const int prep_total = N*64 + 640*64 + 128*64 + 1280 + 128;

  k_zero   <<<dim3((N+255)/256), dim3(256), 0, stream>>>(deg, N);
  k_zero   <<<dim3((G*128+255)/256), dim3(256), 0, stream>>>(gbuf, G*128);
  k_hist   <<<dim3((E+255)/256), dim3(256), 0, stream>>>(dst, deg, E);
  k_scan   <<<dim3(1),           dim3(1024),0, stream>>>(deg, off, cur, N);
  k_scatter<<<dim3((E+255)/256), dim3(256), 0, stream>>>(src, dst, cur, srcs, E);
  k_prep   <<<dim3((prep_total+255)/256), dim3(256), 0, stream>>>(x, W1, W2, al1, ar1, al2, ar2,
                                                                  xh, w1t, w2t, qal1, qar1, qal2, qar2, N*64);

  // layer 1
  k_coef1  <<<dim3(nwB), dim3(256), 0, stream>>>(x, qal1, qar1, el1, er1, N);
  k_gel1   <<<dim3((E*16+255)/256), dim3(256), 0, stream>>>(srcs, el1, ge16, E);
  k_edge1  <<<dim3(N), dim3(64), 0, stream>>>(xh, ge16, er1, off, srcs, aggh, N);
  k_ep1    <<<dim3(gx), dim3(256), 0, stream>>>(aggh, w1t, b1, h1h, qal2, qar2, el2, er2, N);

  // layer 2
  k_gel2   <<<dim3((E+255)/256), dim3(256), 0, stream>>>(srcs, el2, ge2, E);
  k_edge2  <<<dim3(N), dim3(64), 0, stream>>>(h1h, ge2, er2, off, srcs, agg2h, N);
  k_l2     <<<dim3(gx, 2), dim3(256), 0, stream>>>(agg2h, w2t, b2, h2, N);

  // readout: node-parallel segmented max + tiny MLP
  k_gmax   <<<dim3(gx), dim3(256), 0, stream>>>(h2, gid, gbuf, N);
  k_mlp    <<<dim3(G), dim3(128), 0, stream>>>(gbuf, lw1, lb1, lw2, lb2, out);
}

// Round 12
// 230.999 us; speedup vs baseline: 1.2395x; 1.0059x over previous
//
#include <hip/hip_runtime.h>
#include <hip/hip_fp16.h>
#include <math.h>

typedef _Float16 half8 __attribute__((ext_vector_type(8)));
typedef float floatx4 __attribute__((ext_vector_type(4)));

__device__ __forceinline__ float leaky(float v){ return v > 0.f ? v : 0.2f*v; }

__device__ __forceinline__ float wredsum(float v){
  #pragma unroll
  for (int o=32;o>0;o>>=1) v += __shfl_xor(v,o,64);
  return v;
}

// ---------------- graph CSR build (by dst) ----------------
__global__ void k_zero2(int* __restrict__ a, int na, int* __restrict__ b, int nb){
  int i = blockIdx.x*blockDim.x + threadIdx.x;
  if (i < na){ a[i] = 0; return; }
  i -= na;
  if (i < nb) b[i] = 0;
}

__global__ void k_hist(const int* __restrict__ dst, int* __restrict__ deg, int E){
  int i = blockIdx.x*blockDim.x + threadIdx.x;
  if (i < E) atomicAdd(&deg[dst[i]], 1);
}

__global__ __launch_bounds__(1024) void k_scan(const int* __restrict__ deg, int* __restrict__ off,
                                               int* __restrict__ cur, int N){
  __shared__ int part[1024];
  int t = threadIdx.x;
  int chunk = (N + 1023) >> 10;
  int c0 = t * chunk;
  int sum = 0;
  for (int i=0;i<chunk;i++){ int idx=c0+i; if (idx < N) sum += deg[idx]; }
  part[t] = sum;
  __syncthreads();
  for (int o=1;o<1024;o<<=1){
    int v = (t >= o) ? part[t-o] : 0;
    __syncthreads();
    part[t] += v;
    __syncthreads();
  }
  int run = part[t] - sum;   // exclusive prefix of this chunk
  for (int i=0;i<chunk;i++){
    int idx = c0+i;
    if (idx < N){ off[idx] = run; cur[idx] = run; run += deg[idx]; }
  }
  if (t == 1023) off[N] = part[1023];
}

__global__ void k_scatter(const int* __restrict__ src, const int* __restrict__ dst,
                          int* __restrict__ cur, int* __restrict__ srcs, int E){
  int i = blockIdx.x*blockDim.x + threadIdx.x;
  if (i < E){ int p = atomicAdd(&cur[dst[i]], 1); srcs[p] = src[i]; }
}

// ---------------- prep: fp16 casts, weight transposes, folded coef vectors ----------------
__global__ void k_prep(const float* __restrict__ x, const float* __restrict__ W1,
                       const float* __restrict__ W2,
                       const float* __restrict__ al1, const float* __restrict__ ar1,
                       const float* __restrict__ al2, const float* __restrict__ ar2,
                       __half* __restrict__ xh, __half* __restrict__ w1t, __half* __restrict__ w2t,
                       float* __restrict__ qal1, float* __restrict__ qar1,
                       float* __restrict__ qal2, float* __restrict__ qar2, int nx){
  int i = blockIdx.x*blockDim.x + threadIdx.x;
  if (i < nx){ xh[i] = __float2half(x[i]); return; }
  i -= nx;
  if (i < 640*64){ int c = i >> 6, k = i & 63; w1t[i] = __float2half(W1[k*640 + c]); return; }
  i -= 640*64;
  if (i < 128*64){ int c = i >> 6, k = i & 63; w2t[i] = __float2half(W2[k*128 + c]); return; }
  i -= 128*64;
  if (i < 1280){
    int which = i / 640; int j = i - which*640; int k = j / 10, h = j - k*10;
    const float* av = which ? ar1 : al1;
    float s = 0.f;
    for (int c=0;c<64;c++) s += W1[k*640 + h*64 + c] * av[h*64 + c];
    (which ? qar1 : qal1)[k*10 + h] = s;
    return;
  }
  i -= 1280;
  if (i < 128){
    int which = i >> 6; int k = i & 63;
    const float* av = which ? ar2 : al2;
    float s = 0.f;
    for (int c=0;c<128;c++) s += W2[k*128 + c] * av[c];
    (which ? qar2 : qal2)[k] = s;
    return;
  }
}

// ---------------- layer1 coefs via folded vectors ----------------
__global__ __launch_bounds__(256) void k_coef1(const float* __restrict__ x,
                                               const float* __restrict__ qal, const float* __restrict__ qar,
                                               float* __restrict__ el, float* __restrict__ er, int N){
  int n = blockIdx.x*4 + (threadIdx.x>>6);
  int lane = threadIdx.x & 63;
  if (n >= N) return;
  float xv = x[(size_t)n*64 + lane];
  #pragma unroll
  for (int h=0; h<10; h++){
    float pl = wredsum(xv * qal[lane*10 + h]);
    float pr = wredsum(xv * qar[lane*10 + h]);
    if (lane == 0){ el[n*10+h] = pl; er[n*10+h] = pr; }
  }
}

// ---------------- layer1 aggregation via per-node MFMA; logits gathered from L2-resident el ----------------
// agg[10x64] = softmaxW[10xdeg] @ X[degx64].  mfma 16x16x32 f16, K-chunks of 32 edges.
// A lane map: row(head)=l&15, k=(l>>4)*8+j.  B: col=l&15, same k.  D: col=l&15, row=(l>>4)*4+reg.
// First chunk's srcs + logits cached in registers (covers deg<=32, ~all nodes).
__global__ __launch_bounds__(64) void k_edge1(const __half* __restrict__ xh,
                                              const float* __restrict__ el,
                                              const float* __restrict__ er,
                                              const int* __restrict__ off,
                                              const int* __restrict__ srcs,
                                              __half* __restrict__ aggh, int N){
  const int l = threadIdx.x;
  const int n = blockIdx.x;
  const int lr = l & 15, lk = l >> 4;
  const int beg = off[n], end = off[n+1];
  const float erh = (lr < 10) ? er[n*10 + lr] : 0.f;
  // first chunk: srcs + logits into registers
  const int sv0 = (beg + l < end) ? srcs[beg + l] : 0;
  int sj0[8];
  #pragma unroll
  for (int j=0;j<8;j++) sj0[j] = __shfl(sv0, lk*8 + j, 64);
  float lg0[8];
  #pragma unroll
  for (int j=0;j<8;j++){
    int p = beg + lk*8 + j;
    lg0[j] = (p < end && lr < 10) ? el[sj0[j]*10 + lr] : -INFINITY;
  }
  // pass A: per-head max
  float m = -INFINITY;
  #pragma unroll
  for (int j=0;j<8;j++) m = fmaxf(m, lg0[j]);
  for (int c0 = beg + 32; c0 < end; c0 += 32){
    int sv = (c0 + l < end) ? srcs[c0 + l] : 0;
    #pragma unroll
    for (int j=0;j<8;j++){
      int p = c0 + lk*8 + j;
      int sj = __shfl(sv, lk*8 + j, 64);
      float lg = (p < end && lr < 10) ? el[sj*10 + lr] : -INFINITY;
      m = fmaxf(m, lg);
    }
  }
  m = fmaxf(m, __shfl_xor(m,16,64));
  m = fmaxf(m, __shfl_xor(m,32,64));
  m = (lr < 10) ? leaky(m + erh) : 0.f;
  // pass B: w = exp(leaky(el+er)-m) <= 1 (fp16-safe), MFMA accumulate
  float s = 0.f;
  floatx4 acc0 = {0.f,0.f,0.f,0.f}, acc1 = {0.f,0.f,0.f,0.f};
  floatx4 acc2 = {0.f,0.f,0.f,0.f}, acc3 = {0.f,0.f,0.f,0.f};
  for (int c0 = beg; c0 < end; c0 += 32){
    const bool first = (c0 == beg);
    int sv = first ? sv0 : ((c0 + l < end) ? srcs[c0 + l] : 0);
    int sj[8];
    #pragma unroll
    for (int j=0;j<8;j++) sj[j] = first ? sj0[j] : __shfl(sv, lk*8 + j, 64);
    half8 aw;
    #pragma unroll
    for (int j=0;j<8;j++){
      int p = c0 + lk*8 + j;
      float wv = 0.f;
      if (p < end && lr < 10){
        float lg = first ? lg0[j] : el[sj[j]*10 + lr];
        wv = __expf(leaky(lg + erh) - m);
      }
      aw[j] = (_Float16)wv;
      s += (float)aw[j];
    }
    half8 b0, b1, b2, b3;
    #pragma unroll
    for (int j=0;j<8;j++){
      const __half* rp = xh + (size_t)sj[j]*64;
      b0[j] = *(const _Float16*)(rp + lr);
      b1[j] = *(const _Float16*)(rp + 16 + lr);
      b2[j] = *(const _Float16*)(rp + 32 + lr);
      b3[j] = *(const _Float16*)(rp + 48 + lr);
    }
    acc0 = __builtin_amdgcn_mfma_f32_16x16x32_f16(aw, b0, acc0, 0, 0, 0);
    acc1 = __builtin_amdgcn_mfma_f32_16x16x32_f16(aw, b1, acc1, 0, 0, 0);
    acc2 = __builtin_amdgcn_mfma_f32_16x16x32_f16(aw, b2, acc2, 0, 0, 0);
    acc3 = __builtin_amdgcn_mfma_f32_16x16x32_f16(aw, b3, acc3, 0, 0, 0);
  }
  s += __shfl_xor(s,16,64);
  s += __shfl_xor(s,32,64);
  const float rs = (lr < 10 && s > 0.f) ? 1.f/s : 0.f;
  #pragma unroll
  for (int j=0;j<4;j++){
    int h = lk*4 + j;
    float rj = __shfl(rs, h, 64);
    if (h < 10){
      __half* op = aggh + (size_t)n*640 + h*64;
      op[lr]      = __float2half(acc0[j] * rj);
      op[16 + lr] = __float2half(acc1[j] * rj);
      op[32 + lr] = __float2half(acc2[j] * rj);
      op[48 + lr] = __float2half(acc3[j] * rj);
    }
  }
}

// ---------------- layer1 post-GEMM + fused layer2 coefs ----------------
__global__ __launch_bounds__(256) void k_ep1(const __half* __restrict__ aggh,
                                             const __half* __restrict__ w1t,
                                             const float* __restrict__ bias1,
                                             __half* __restrict__ h1h,
                                             const float* __restrict__ qal2,
                                             const float* __restrict__ qar2,
                                             float* __restrict__ el2, float* __restrict__ er2, int M){
  const int w = threadIdx.x >> 6, l = threadIdx.x & 63;
  const int m0 = blockIdx.x*64 + w*16;
  const int lr = l & 15, lk = l >> 4;
  int arow = m0 + lr; if (arow >= M) arow = M-1;
  float hsum[4][4];
  #pragma unroll
  for (int t=0;t<4;t++)
    #pragma unroll
    for (int j=0;j<4;j++) hsum[t][j] = 0.f;
  for (int h=0;h<10;h++){
    const __half* ap = aggh + (size_t)arow*640 + h*64;
    half8 a0 = *reinterpret_cast<const half8*>(ap + lk*8);
    half8 a1 = *reinterpret_cast<const half8*>(ap + 32 + lk*8);
    #pragma unroll
    for (int t=0;t<4;t++){
      const __half* bp = w1t + (size_t)(h*64 + t*16 + lr)*64 + lk*8;
      half8 b0 = *reinterpret_cast<const half8*>(bp);
      half8 b1 = *reinterpret_cast<const half8*>(bp + 32);
      floatx4 z = {0.f,0.f,0.f,0.f};
      z = __builtin_amdgcn_mfma_f32_16x16x32_f16(a0, b0, z, 0, 0, 0);
      z = __builtin_amdgcn_mfma_f32_16x16x32_f16(a1, b1, z, 0, 0, 0);
      float bb = bias1[h*64 + t*16 + lr];
      #pragma unroll
      for (int j=0;j<4;j++) hsum[t][j] += fmaxf(z[j] + bb, 0.f);
    }
  }
  #pragma unroll
  for (int t=0;t<4;t++)
    #pragma unroll
    for (int j=0;j<4;j++){
      int r = m0 + lk*4 + j;
      if (r < M) h1h[(size_t)r*64 + t*16 + lr] = __float2half(hsum[t][j]);
    }
  float pl[4] = {0,0,0,0}, pr[4] = {0,0,0,0};
  #pragma unroll
  for (int t=0;t<4;t++){
    float qa = qal2[t*16 + lr];
    float qr = qar2[t*16 + lr];
    #pragma unroll
    for (int j=0;j<4;j++){ pl[j] += hsum[t][j]*qa; pr[j] += hsum[t][j]*qr; }
  }
  #pragma unroll
  for (int o=1;o<16;o<<=1)
    #pragma unroll
    for (int j=0;j<4;j++){ pl[j] += __shfl_xor(pl[j],o,64); pr[j] += __shfl_xor(pr[j],o,64); }
  if (lr == 0){
    #pragma unroll
    for (int j=0;j<4;j++){
      int r = m0 + lk*4 + j;
      if (r < M){ el2[r] = pl[j]; er2[r] = pr[j]; }
    }
  }
}

// ---------------- layer2 aggregation (logits gathered from L2-resident el2; no max pass) ----------------
__global__ __launch_bounds__(64) void k_edge2(const __half* __restrict__ h1h,
                                              const float* __restrict__ el2,
                                              const float* __restrict__ er,
                                              const int* __restrict__ off,
                                              const int* __restrict__ srcs,
                                              __half* __restrict__ agg2h, int N){
  const int lane = threadIdx.x;
  const int n = blockIdx.x;
  const int beg = off[n], end = off[n+1];
  const float ern = er[n];
  float s = 0.f, acc = 0.f;
  for (int c0 = beg; c0 < end; c0 += 64){
    const bool vl = (c0 + lane < end);
    const int sv = vl ? srcs[c0 + lane] : 0;
    const float gv = vl ? el2[sv] : -INFINITY;
    const float wv = __expf(leaky(gv + ern));   // softmax shift-invariant; pad -> 0
    s += wv;
    const int cn = min(64, end - c0);
    for (int j = 0; j < cn; j += 8){
      const int nv = min(8, cn - j);
      float hv[8], wj[8];
      #pragma unroll
      for (int jj=0;jj<8;jj++){
        if (jj < nv){
          int sj = __shfl(sv, j+jj, 64);
          hv[jj] = __half2float(h1h[(size_t)sj*64 + lane]);
          wj[jj] = __shfl(wv, j+jj, 64);
        }
      }
      #pragma unroll
      for (int jj=0;jj<8;jj++) if (jj < nv) acc += wj[jj]*hv[jj];
    }
  }
  s = wredsum(s);
  const float rs = (s > 0.f) ? 1.f/s : 0.f;
  agg2h[(size_t)n*64 + lane] = __float2half(acc * rs);
}

// ---------------- layer2 post-GEMM fused with per-graph max ----------------
// h2 = relu(agg2 @ W2 + b2) >= 0 -> int-bit atomicMax into gbuf (init 0, matches empty-graph clamp)
__global__ __launch_bounds__(256) void k_l2(const __half* __restrict__ ah,
                                            const __half* __restrict__ wt,
                                            const float* __restrict__ bias2,
                                            const int* __restrict__ gid,
                                            int* __restrict__ gbuf, int M){
  const int w = threadIdx.x >> 6, l = threadIdx.x & 63;
  const int m0 = blockIdx.x*64 + w*16;
  const int c0 = blockIdx.y*64;
  const int lr = l & 15, lk = l >> 4;
  int arow = m0 + lr; if (arow >= M) arow = M-1;
  half8 a0 = *reinterpret_cast<const half8*>(ah + (size_t)arow*64 + lk*8);
  half8 a1 = *reinterpret_cast<const half8*>(ah + (size_t)arow*64 + 32 + lk*8);
  int g4[4];
  #pragma unroll
  for (int j=0;j<4;j++){
    int r = m0 + lk*4 + j;
    g4[j] = (r < M) ? gid[r] : 0;
  }
  #pragma unroll
  for (int t=0;t<4;t++){
    const __half* bp = wt + (size_t)(c0 + t*16 + lr)*64 + lk*8;
    half8 b0 = *reinterpret_cast<const half8*>(bp);
    half8 b1 = *reinterpret_cast<const half8*>(bp + 32);
    floatx4 z = {0.f,0.f,0.f,0.f};
    z = __builtin_amdgcn_mfma_f32_16x16x32_f16(a0, b0, z, 0, 0, 0);
    z = __builtin_amdgcn_mfma_f32_16x16x32_f16(a1, b1, z, 0, 0, 0);
    float bb = bias2[c0 + t*16 + lr];
    #pragma unroll
    for (int j=0;j<4;j++){
      int r = m0 + lk*4 + j;
      if (r < M){
        float v = fmaxf(z[j] + bb, 0.f);
        atomicMax(&gbuf[g4[j]*128 + c0 + t*16 + lr], __float_as_int(v));
      }
    }
  }
}

// ---------------- per-graph 2-layer MLP ----------------
__global__ __launch_bounds__(128) void k_mlp(const int* __restrict__ g,
                                             const float* __restrict__ lw1, const float* __restrict__ lb1,
                                             const float* __restrict__ lw2, const float* __restrict__ lb2,
                                             float* __restrict__ out){
  int b = blockIdx.x, t = threadIdx.x;
  __shared__ float gs[128];
  __shared__ float ys[128];
  gs[t] = __int_as_float(g[b*128 + t]);
  __syncthreads();
  float y = lb1[t];
  for (int k=0;k<128;k++) y += gs[k]*lw1[k*128 + t];
  y = fmaxf(y, 0.f);
  ys[t] = y * lw2[t];
  __syncthreads();
  for (int o=64;o>0;o>>=1){
    if (t < o) ys[t] += ys[t+o];
    __syncthreads();
  }
  if (t == 0) out[b] = fmaxf(ys[0] + lb2[0], 0.f);
}

extern "C" void kernel_launch(void* const* d_in, const int* in_sizes, int n_in,
                              void* d_out, int out_size, void* d_ws, size_t ws_size,
                              hipStream_t stream){
  const float* x   = (const float*)d_in[0];
  const int*   src = (const int*)d_in[1];
  const int*   dst = (const int*)d_in[2];
  const int*   gid = (const int*)d_in[3];
  const float* W1  = (const float*)d_in[4];
  const float* al1 = (const float*)d_in[5];
  const float* ar1 = (const float*)d_in[6];
  const float* b1  = (const float*)d_in[7];
  const float* W2  = (const float*)d_in[8];
  const float* al2 = (const float*)d_in[9];
  const float* ar2 = (const float*)d_in[10];
  const float* b2  = (const float*)d_in[11];
  const float* lw1 = (const float*)d_in[12];
  const float* lb1 = (const float*)d_in[13];
  const float* lw2 = (const float*)d_in[14];
  const float* lb2 = (const float*)d_in[15];
  float* out = (float*)d_out;

  const int N = in_sizes[0] / 64;
  const int E = in_sizes[1];
  const int G = out_size;

  char* w = (char*)d_ws;
  size_t p = 0;
  auto alloc = [&](size_t bytes)->char*{ char* r = w + p; p += (bytes + 255) & ~size_t(255); return r; };
  int*    deg   = (int*)alloc((size_t)N*4);
  int*    off   = (int*)alloc((size_t)(N+1)*4);
  int*    cur   = (int*)alloc((size_t)N*4);
  int*    srcs  = (int*)alloc((size_t)E*4);
  float*  el1   = (float*)alloc((size_t)N*10*4);
  float*  er1   = (float*)alloc((size_t)N*10*4);
  __half* xh    = (__half*)alloc((size_t)N*64*2);
  __half* w1t   = (__half*)alloc((size_t)640*64*2);
  __half* w2t   = (__half*)alloc((size_t)128*64*2);
  float*  qal1  = (float*)alloc((size_t)640*4);
  float*  qar1  = (float*)alloc((size_t)640*4);
  float*  qal2  = (float*)alloc((size_t)64*4);
  float*  qar2  = (float*)alloc((size_t)64*4);
  __half* aggh  = (__half*)alloc((size_t)N*640*2);
  __half* h1h   = (__half*)alloc((size_t)N*64*2);
  __half* agg2h = (__half*)alloc((size_t)N*64*2);
  int*    gbuf  = (int*)alloc((size_t)G*128*4);
  float*  el2 = el1;
  float*  er2 = er1;

  const int nwB = (N + 3) / 4;
  const int gx  = (N + 63) / 64;
  const int prep_total = N*64 + 640*64 + 128*64 + 1280 + 128;
  const int zero_total = N + G*128;

  k_zero2  <<<dim3((zero_total+255)/256), dim3(256), 0, stream>>>(deg, N, gbuf, G*128);
  k_hist   <<<dim3((E+255)/256), dim3(256), 0, stream>>>(dst, deg, E);
  k_scan   <<<dim3(1),           dim3(1024),0, stream>>>(deg, off, cur, N);
  k_scatter<<<dim3((E+255)/256), dim3(256), 0, stream>>>(src, dst, cur, srcs, E);
  k_prep   <<<dim3((prep_total+255)/256), dim3(256), 0, stream>>>(x, W1, W2, al1, ar1, al2, ar2,
                                                                  xh, w1t, w2t, qal1, qar1, qal2, qar2, N*64);

  // layer 1
  k_coef1  <<<dim3(nwB), dim3(256), 0, stream>>>(x, qal1, qar1, el1, er1, N);
  k_edge1  <<<dim3(N), dim3(64), 0, stream>>>(xh, el1, er1, off, srcs, aggh, N);
  k_ep1    <<<dim3(gx), dim3(256), 0, stream>>>(aggh, w1t, b1, h1h, qal2, qar2, el2, er2, N);

  // layer 2
  k_edge2  <<<dim3(N), dim3(64), 0, stream>>>(h1h, el2, er2, off, srcs, agg2h, N);
  k_l2     <<<dim3(gx, 2), dim3(256), 0, stream>>>(agg2h, w2t, b2, gid, gbuf, N);

  // readout MLP
  k_mlp    <<<dim3(G), dim3(128), 0, stream>>>(gbuf, lw1, lb1, lw2, lb2, out);
}